// Round 7
// baseline (175.740 us; speedup 1.0000x reference)
//
#include <hip/hip_runtime.h>

#define IN_DIM   256
#define HID_DIM  512
#define OUT_DIM  256
#define N_CHILD  8
#define BATCH    1024

#define SB    32   // samples per chunk
#define XPAD  36   // [k][s] LDS row stride (floats), 16B-aligned
#define MAXCH 96   // sum ceil(n_a/32) <= 32 + 64*31/32 < 96

// ---------------- prep: counting-sort samples by agent, build chunk list ----
// agent_indices may be int32 or int64 (jax_enable_x64): view as int32; if any
// odd word != 0 it's int32, else int64 (odd slots are zero high words).
extern "C" __global__ __launch_bounds__(1024)
void prep_sort(const int* __restrict__ raw, int* __restrict__ sorted,
               int* __restrict__ ch_agent, int* __restrict__ ch_start,
               int* __restrict__ ch_len)
{
    __shared__ int cnt[64], start[64];
    __shared__ int is32;
    const int t = threadIdx.x;
    if (t < 64) cnt[t] = 0;
    if (t == 0) is32 = 0;
    __syncthreads();
    if (raw[2 * (t & 511) + 1] != 0) is32 = 1;   // benign shared race
    __syncthreads();
    const int a = (is32 ? raw[t] : raw[2 * t]) & 63;
    atomicAdd(&cnt[a], 1);
    __syncthreads();
    if (t == 0) {
        int off = 0, nch = 0;
        for (int i = 0; i < 64; ++i) {
            start[i] = off;
            const int c = cnt[i];
            for (int p = 0; p < c; p += SB) {
                ch_agent[nch] = i;
                ch_start[nch] = off + p;
                ch_len[nch]   = (c - p < SB) ? (c - p) : SB;
                ++nch;
            }
            off += c;
        }
        for (; nch < MAXCH; ++nch) ch_len[nch] = 0;
    }
    __syncthreads();
    if (t < 64) cnt[t] = 0;
    __syncthreads();
    const int pos = start[a] + atomicAdd(&cnt[a], 1);
    sorted[pos] = t;
}

// ---------------- K1: H = relu(X @ W1[a] + b1[a])  (256 -> 512) -------------
// grid (MAXCH, 4 tiles of 128 cols), 256 thr.
// lane map: cg=t&15 (8 cols as cg*4 / 64+cg*4), kq=(t>>4)&3 (in-wave K-split),
// sg=t>>6 (wave owns 8 samples). Waves with sg*8>=len skip compute.
extern "C" __global__ __launch_bounds__(256)
void k1_mlp1(const float* __restrict__ x, const float* __restrict__ W1,
             const float* __restrict__ b1,
             const int* __restrict__ sorted, const int* __restrict__ ch_agent,
             const int* __restrict__ ch_start, const int* __restrict__ ch_len,
             float* __restrict__ h_out)
{
    const int chunk = blockIdx.x;
    const int len = ch_len[chunk];
    if (len == 0) return;
    const int a  = ch_agent[chunk];
    const int cs = ch_start[chunk];
    const int t  = threadIdx.x;
    const int bcol = blockIdx.y * 128;

    __shared__ float xsT[64 * XPAD];      // per-pass x rows, [k][s]
    __shared__ float wS[64 * 128];        // per-pass W tile, 32 KB
    __shared__ int   sidS[SB];

    if (t < SB) sidS[t] = sorted[cs + (t < len ? t : len - 1)]; // pad = dup
    __syncthreads();

    const int cg = t & 15;
    const int kq = (t >> 4) & 3;
    const int sg = t >> 6;
    const bool act = (sg * 8) < len;
    const float* Wb = W1 + (size_t)a * IN_DIM * HID_DIM + bcol;

    float acc[64];
    #pragma unroll
    for (int i = 0; i < 64; ++i) acc[i] = 0.f;

    for (int p = 0; p < IN_DIM / 64; ++p) {          // 4 passes
        const int k0 = p * 64;
        __syncthreads();
        {   // stage x rows k0..k0+63 for 32 samples (coalesced over k)
            const int kr = t & 63;
            const int sb = (t >> 6) * 8;
            #pragma unroll
            for (int i = 0; i < 8; ++i)
                xsT[kr * XPAD + sb + i] =
                    x[(size_t)sidS[sb + i] * IN_DIM + k0 + kr];
        }
        #pragma unroll
        for (int i = 0; i < 8; ++i) {                 // stage 32 KB W tile
            const int id  = t + i * 256;
            const int row = id >> 5;
            const int c4  = (id & 31) * 4;
            *(float4*)(&wS[row * 128 + c4]) =
                *(const float4*)(Wb + (size_t)(k0 + row) * HID_DIM + c4);
        }
        __syncthreads();
        if (act) {
            #pragma unroll
            for (int i = 0; i < 16; ++i) {
                const int row = i * 4 + kq;           // kq-interleaved rows
                const float4 w0 = *(const float4*)(&wS[row * 128 + cg * 4]);
                const float4 w1 = *(const float4*)(&wS[row * 128 + 64 + cg * 4]);
                const float4 xa = *(const float4*)(&xsT[row * XPAD + sg * 8]);
                const float4 xb = *(const float4*)(&xsT[row * XPAD + sg * 8 + 4]);
                const float wv[8] = {w0.x, w0.y, w0.z, w0.w, w1.x, w1.y, w1.z, w1.w};
                const float xv[8] = {xa.x, xa.y, xa.z, xa.w, xb.x, xb.y, xb.z, xb.w};
                #pragma unroll
                for (int c = 0; c < 8; ++c)
                    #pragma unroll
                    for (int s = 0; s < 8; ++s)
                        acc[c * 8 + s] = fmaf(wv[c], xv[s], acc[c * 8 + s]);
            }
        }
    }

    if (act) {
        #pragma unroll
        for (int i = 0; i < 64; ++i) {               // reduce over kq (lanes^16,^32)
            acc[i] += __shfl_xor(acc[i], 16);
            acc[i] += __shfl_xor(acc[i], 32);
        }
        if (kq == 0) {
            const float4 bA = *(const float4*)(b1 + a * HID_DIM + bcol + cg * 4);
            const float4 bB = *(const float4*)(b1 + a * HID_DIM + bcol + 64 + cg * 4);
            #pragma unroll
            for (int s = 0; s < 8; ++s) {
                float* hp = h_out + (size_t)sidS[sg * 8 + s] * HID_DIM + bcol;
                float4 v0, v1;
                v0.x = fmaxf(acc[0 * 8 + s] + bA.x, 0.f);
                v0.y = fmaxf(acc[1 * 8 + s] + bA.y, 0.f);
                v0.z = fmaxf(acc[2 * 8 + s] + bA.z, 0.f);
                v0.w = fmaxf(acc[3 * 8 + s] + bA.w, 0.f);
                v1.x = fmaxf(acc[4 * 8 + s] + bB.x, 0.f);
                v1.y = fmaxf(acc[5 * 8 + s] + bB.y, 0.f);
                v1.z = fmaxf(acc[6 * 8 + s] + bB.z, 0.f);
                v1.w = fmaxf(acc[7 * 8 + s] + bB.w, 0.f);
                *(float4*)(hp + cg * 4)      = v0;   // dup-slot writes identical
                *(float4*)(hp + 64 + cg * 4) = v1;
            }
        }
    }
}

// ---------------- K2: OUT = H @ W2[a] + b2[a]  (512 -> 256) -----------------
// grid (MAXCH, 4 tiles of 64 cols), 256 thr.
// lane map: cg=t&7 (8 cols as cg*4 / 32+cg*4), kq=(t>>3)&7, sg=t>>6.
extern "C" __global__ __launch_bounds__(256)
void k2_mlp2(const float* __restrict__ h, const float* __restrict__ W2,
             const float* __restrict__ b2,
             const int* __restrict__ sorted, const int* __restrict__ ch_agent,
             const int* __restrict__ ch_start, const int* __restrict__ ch_len,
             float* __restrict__ o_out)
{
    const int chunk = blockIdx.x;
    const int len = ch_len[chunk];
    if (len == 0) return;
    const int a  = ch_agent[chunk];
    const int cs = ch_start[chunk];
    const int t  = threadIdx.x;
    const int bcol = blockIdx.y * 64;

    __shared__ float hsT[64 * XPAD];      // per-pass h rows, [k][s]
    __shared__ float wS[64 * 64];         // per-pass W tile, 16 KB
    __shared__ int   sidS[SB];

    if (t < SB) sidS[t] = sorted[cs + (t < len ? t : len - 1)];
    __syncthreads();

    const int cg = t & 7;
    const int kq = (t >> 3) & 7;
    const int sg = t >> 6;
    const bool act = (sg * 8) < len;
    const float* Wb = W2 + (size_t)a * HID_DIM * OUT_DIM + bcol;

    float acc[64];
    #pragma unroll
    for (int i = 0; i < 64; ++i) acc[i] = 0.f;

    for (int p = 0; p < HID_DIM / 64; ++p) {         // 8 passes
        const int k0 = p * 64;
        __syncthreads();
        {   // stage h rows (coalesced over k)
            const int kr = t & 63;
            const int sb = (t >> 6) * 8;
            #pragma unroll
            for (int i = 0; i < 8; ++i)
                hsT[kr * XPAD + sb + i] =
                    h[(size_t)sidS[sb + i] * HID_DIM + k0 + kr];
        }
        #pragma unroll
        for (int i = 0; i < 4; ++i) {                 // stage 16 KB W tile
            const int id  = t + i * 256;
            const int row = id >> 4;
            const int c4  = (id & 15) * 4;
            *(float4*)(&wS[row * 64 + c4]) =
                *(const float4*)(Wb + (size_t)(k0 + row) * OUT_DIM + c4);
        }
        __syncthreads();
        if (act) {
            #pragma unroll
            for (int i = 0; i < 8; ++i) {
                const int row = i * 8 + kq;
                const float4 w0 = *(const float4*)(&wS[row * 64 + cg * 4]);
                const float4 w1 = *(const float4*)(&wS[row * 64 + 32 + cg * 4]);
                const float4 xa = *(const float4*)(&hsT[row * XPAD + sg * 8]);
                const float4 xb = *(const float4*)(&hsT[row * XPAD + sg * 8 + 4]);
                const float wv[8] = {w0.x, w0.y, w0.z, w0.w, w1.x, w1.y, w1.z, w1.w};
                const float xv[8] = {xa.x, xa.y, xa.z, xa.w, xb.x, xb.y, xb.z, xb.w};
                #pragma unroll
                for (int c = 0; c < 8; ++c)
                    #pragma unroll
                    for (int s = 0; s < 8; ++s)
                        acc[c * 8 + s] = fmaf(wv[c], xv[s], acc[c * 8 + s]);
            }
        }
    }

    if (act) {
        #pragma unroll
        for (int i = 0; i < 64; ++i) {               // reduce over kq (^8,^16,^32)
            acc[i] += __shfl_xor(acc[i], 8);
            acc[i] += __shfl_xor(acc[i], 16);
            acc[i] += __shfl_xor(acc[i], 32);
        }
        if (kq == 0) {
            const float4 bA = *(const float4*)(b2 + a * OUT_DIM + bcol + cg * 4);
            const float4 bB = *(const float4*)(b2 + a * OUT_DIM + bcol + 32 + cg * 4);
            #pragma unroll
            for (int s = 0; s < 8; ++s) {
                float* op = o_out + (size_t)sidS[sg * 8 + s] * OUT_DIM + bcol;
                float4 v0, v1;
                v0.x = acc[0 * 8 + s] + bA.x;
                v0.y = acc[1 * 8 + s] + bA.y;
                v0.z = acc[2 * 8 + s] + bA.z;
                v0.w = acc[3 * 8 + s] + bA.w;
                v1.x = acc[4 * 8 + s] + bB.x;
                v1.y = acc[5 * 8 + s] + bB.y;
                v1.z = acc[6 * 8 + s] + bB.z;
                v1.w = acc[7 * 8 + s] + bB.w;
                *(float4*)(op + cg * 4)      = v0;
                *(float4*)(op + 32 + cg * 4) = v1;
            }
        }
    }
}

// ---------------- K3: R = H @ rw[a]  (512 -> 8) -----------------------------
// grid MAXCH, 256 thr: c = t&7, s = t>>3 (32 samples), serial K.
extern "C" __global__ __launch_bounds__(256)
void k3_router(const float* __restrict__ h, const float* __restrict__ rw,
               const int* __restrict__ sorted, const int* __restrict__ ch_agent,
               const int* __restrict__ ch_start, const int* __restrict__ ch_len,
               float* __restrict__ r_out)
{
    const int chunk = blockIdx.x;
    const int len = ch_len[chunk];
    if (len == 0) return;
    const int a  = ch_agent[chunk];
    const int cs = ch_start[chunk];
    const int t  = threadIdx.x;

    __shared__ int sidS[SB];
    if (t < SB) sidS[t] = sorted[cs + (t < len ? t : len - 1)];
    __syncthreads();

    const int c = t & 7;
    const int s = t >> 3;
    const float* hv = h  + (size_t)sidS[s] * HID_DIM;
    const float* rv = rw + (size_t)a * HID_DIM * N_CHILD + c;
    float p = 0.f;
    #pragma unroll 4
    for (int k4 = 0; k4 < HID_DIM / 4; ++k4) {
        const float4 hx = *(const float4*)(hv + k4 * 4);
        p = fmaf(hx.x, rv[(size_t)(k4 * 4 + 0) * N_CHILD], p);
        p = fmaf(hx.y, rv[(size_t)(k4 * 4 + 1) * N_CHILD], p);
        p = fmaf(hx.z, rv[(size_t)(k4 * 4 + 2) * N_CHILD], p);
        p = fmaf(hx.w, rv[(size_t)(k4 * 4 + 3) * N_CHILD], p);
    }
    r_out[(size_t)sidS[s] * N_CHILD + c] = p;
}

extern "C" void kernel_launch(void* const* d_in, const int* in_sizes, int n_in,
                              void* d_out, int out_size, void* d_ws, size_t ws_size,
                              hipStream_t stream) {
    const float* x  = (const float*)d_in[0];
    const float* W1 = (const float*)d_in[1];
    const float* b1 = (const float*)d_in[2];
    const float* W2 = (const float*)d_in[3];
    const float* b2 = (const float*)d_in[4];
    const float* rw = (const float*)d_in[5];
    const int* raw  = (const int*)d_in[6];

    int* ws       = (int*)d_ws;
    int* sorted   = ws;            // [1024]
    int* ch_agent = ws + 1024;     // [96]
    int* ch_start = ws + 1120;     // [96]
    int* ch_len   = ws + 1216;     // [96]

    float* out   = (float*)d_out;
    float* h_out = out;                                   // [B, HID]
    float* o_out = h_out + (size_t)BATCH * HID_DIM;       // [B, OUT]
    float* r_out = o_out + (size_t)BATCH * OUT_DIM;       // [B, C]

    hipLaunchKernelGGL(prep_sort, dim3(1), dim3(1024), 0, stream,
                       raw, sorted, ch_agent, ch_start, ch_len);
    hipLaunchKernelGGL(k1_mlp1, dim3(MAXCH, 4), dim3(256), 0, stream,
                       x, W1, b1, sorted, ch_agent, ch_start, ch_len, h_out);
    hipLaunchKernelGGL(k2_mlp2, dim3(MAXCH, 4), dim3(256), 0, stream,
                       h_out, W2, b2, sorted, ch_agent, ch_start, ch_len, o_out);
    hipLaunchKernelGGL(k3_router, dim3(MAXCH), dim3(256), 0, stream,
                       h_out, rw, sorted, ch_agent, ch_start, ch_len, r_out);
}

// Round 8
// 144.062 us; speedup vs baseline: 1.2199x; 1.2199x over previous
//
#include <hip/hip_runtime.h>

#define IN_DIM   256
#define HID_DIM  512
#define OUT_DIM  256
#define N_CHILD  8
#define BATCH    1024

#define SB    16   // samples per chunk
#define XPAD  20   // [k][s] LDS stride: 16B-aligned float4 groups
#define MAXCH 128  // sum ceil(n_a/16) <= 64 + 1024/16 = 128

// ---------------- prep: counting-sort samples by agent, build chunk list ----
// agent_indices may be int32 or int64 (jax_enable_x64): view as int32; if any
// odd word != 0 it's int32, else int64 (odd slots are zero high words).
extern "C" __global__ __launch_bounds__(1024)
void prep_sort(const int* __restrict__ raw, int* __restrict__ sorted,
               int* __restrict__ ch_agent, int* __restrict__ ch_start,
               int* __restrict__ ch_len)
{
    __shared__ int cnt[64], start[64];
    __shared__ int is32;
    const int t = threadIdx.x;
    if (t < 64) cnt[t] = 0;
    if (t == 0) is32 = 0;
    __syncthreads();
    if (raw[2 * (t & 511) + 1] != 0) is32 = 1;   // benign shared race
    __syncthreads();
    const int a = (is32 ? raw[t] : raw[2 * t]) & 63;
    atomicAdd(&cnt[a], 1);
    __syncthreads();
    if (t == 0) {
        int off = 0, nch = 0;
        for (int i = 0; i < 64; ++i) {
            start[i] = off;
            const int c = cnt[i];
            for (int p = 0; p < c; p += SB) {
                ch_agent[nch] = i;
                ch_start[nch] = off + p;
                ch_len[nch]   = (c - p < SB) ? (c - p) : SB;
                ++nch;
            }
            off += c;
        }
        for (; nch < MAXCH; ++nch) ch_len[nch] = 0;
    }
    __syncthreads();
    if (t < 64) cnt[t] = 0;
    __syncthreads();
    const int pos = start[a] + atomicAdd(&cnt[a], 1);
    sorted[pos] = t;
}

// ---------------- K1: H = relu(X @ W1[a] + b1[a]); R += H @ rw[a] -----------
// grid (MAXCH, 8 tiles of 64 cols), 256 thr = 4 waves.
// lane map: cg=t&15 (4 cols), kq=(t>>4)&3 (in-wave K-split), wave=t>>6 owns
// samples 4w..4w+3 (gating). W double-buffered per 64-row pass; x staged once.
// Router partials (this block's 64 cols) atomicAdd'ed into r_out.
extern "C" __global__ __launch_bounds__(256)
void k1_mlp1(const float* __restrict__ x, const float* __restrict__ W1,
             const float* __restrict__ b1, const float* __restrict__ rw,
             const int* __restrict__ sorted, const int* __restrict__ ch_agent,
             const int* __restrict__ ch_start, const int* __restrict__ ch_len,
             float* __restrict__ h_out, float* __restrict__ r_out)
{
    const int chunk = blockIdx.x;
    const int len = ch_len[chunk];
    if (len == 0) return;
    const int a  = ch_agent[chunk];
    const int cs = ch_start[chunk];
    const int t  = threadIdx.x;
    const int bcol = blockIdx.y * 64;

    __shared__ float xT[IN_DIM * XPAD];      // 20 KB, [k][s], staged once
    __shared__ float wS[2][64 * 64];         // 32 KB, double-buffered W tile
    __shared__ int   sid[SB];

    if (t < SB) sid[t] = sorted[cs + (t < len ? t : len - 1)];   // pad = dup
    __syncthreads();

    // stage all x rows: thread t = k index, 16 coalesced loads
    #pragma unroll
    for (int s = 0; s < SB; ++s)
        xT[t * XPAD + s] = x[(size_t)sid[s] * IN_DIM + t];

    const float* Wb = W1 + (size_t)a * IN_DIM * HID_DIM + bcol;
    // stage W pass 0 into buf 0
    #pragma unroll
    for (int i = 0; i < 4; ++i) {
        const int id  = t + i * 256;
        const int row = id >> 4;
        const int c4  = (id & 15) * 4;
        *(float4*)(&wS[0][row * 64 + c4]) =
            *(const float4*)(Wb + (size_t)row * HID_DIM + c4);
    }
    __syncthreads();

    const int cg = t & 15;
    const int kq = (t >> 4) & 3;
    const int w  = t >> 6;
    const bool act = (w * 4) < len;

    float acc[16];                           // [c][s], c=4 cols, s=4 samples
    #pragma unroll
    for (int i = 0; i < 16; ++i) acc[i] = 0.f;

    for (int p = 0; p < IN_DIM / 64; ++p) {  // 4 passes of 64 k-rows
        if (p < 3) {                         // prefetch next W tile (other buf)
            const int nb = (p + 1) & 1;
            const float* Wp = Wb + (size_t)(p + 1) * 64 * HID_DIM;
            #pragma unroll
            for (int i = 0; i < 4; ++i) {
                const int id  = t + i * 256;
                const int row = id >> 4;
                const int c4  = (id & 15) * 4;
                *(float4*)(&wS[nb][row * 64 + c4]) =
                    *(const float4*)(Wp + (size_t)row * HID_DIM + c4);
            }
        }
        if (act) {
            const float* wb = wS[p & 1];
            #pragma unroll
            for (int i = 0; i < 16; ++i) {
                const int row = kq * 16 + i;
                const float4 wv = *(const float4*)(&wb[row * 64 + cg * 4]);
                const float4 xv = *(const float4*)(&xT[(p * 64 + row) * XPAD + w * 4]);
                const float wa[4] = {wv.x, wv.y, wv.z, wv.w};
                const float xa[4] = {xv.x, xv.y, xv.z, xv.w};
                #pragma unroll
                for (int c = 0; c < 4; ++c)
                    #pragma unroll
                    for (int s = 0; s < 4; ++s)
                        acc[c * 4 + s] = fmaf(wa[c], xa[s], acc[c * 4 + s]);
            }
        }
        __syncthreads();                     // buf p+1 ready; buf p reusable
    }

    if (!act) return;

    // reduce over kq (lane bits 4-5): all lanes end with full sums
    #pragma unroll
    for (int i = 0; i < 16; ++i) {
        acc[i] += __shfl_xor(acc[i], 16);
        acc[i] += __shfl_xor(acc[i], 32);
    }

    const float4 bv = *(const float4*)(b1 + a * HID_DIM + bcol + cg * 4);
    const float ba[4] = {bv.x, bv.y, bv.z, bv.w};
    float hv[16];                            // relu'd h, [c][s]
    #pragma unroll
    for (int c = 0; c < 4; ++c)
        #pragma unroll
        for (int s = 0; s < 4; ++s)
            hv[c * 4 + s] = fmaxf(acc[c * 4 + s] + ba[c], 0.f);

    if (kq == 0) {                           // write h (dup-slot writes identical)
        #pragma unroll
        for (int s = 0; s < 4; ++s) {
            float4 v = make_float4(hv[0 * 4 + s], hv[1 * 4 + s],
                                   hv[2 * 4 + s], hv[3 * 4 + s]);
            *(float4*)(h_out + (size_t)sid[w * 4 + s] * HID_DIM + bcol + cg * 4) = v;
        }
    }

    // router partial over this block's 64 cols (computed redundantly in all kq)
    float rp[32];                            // [s][ch]
    #pragma unroll
    for (int i = 0; i < 32; ++i) rp[i] = 0.f;
    const float* rwa = rw + (size_t)a * HID_DIM * N_CHILD + (size_t)(bcol + cg * 4) * N_CHILD;
    #pragma unroll
    for (int j = 0; j < 4; ++j)
        #pragma unroll
        for (int ch = 0; ch < 8; ++ch) {
            const float rv = rwa[j * N_CHILD + ch];
            #pragma unroll
            for (int s = 0; s < 4; ++s)
                rp[s * 8 + ch] = fmaf(hv[j * 4 + s], rv, rp[s * 8 + ch]);
        }
    #pragma unroll
    for (int i = 0; i < 32; ++i) {           // reduce over cg (lane bits 0-3)
        rp[i] += __shfl_xor(rp[i], 1);
        rp[i] += __shfl_xor(rp[i], 2);
        rp[i] += __shfl_xor(rp[i], 4);
        rp[i] += __shfl_xor(rp[i], 8);
    }
    if (cg == 0 && kq == 0) {
        #pragma unroll
        for (int s = 0; s < 4; ++s) {
            const int sg = w * 4 + s;
            if (sg < len) {
                float* rdst = r_out + (size_t)sid[sg] * N_CHILD;
                #pragma unroll
                for (int ch = 0; ch < 8; ++ch)
                    atomicAdd(rdst + ch, rp[s * 8 + ch]);
            }
        }
    }
}

// ---------------- K2: OUT = H @ W2[a] + b2[a]  (512 -> 256) -----------------
// grid (MAXCH, 4 tiles of 64 cols), 256 thr. Same map; W and h double-buffered.
extern "C" __global__ __launch_bounds__(256)
void k2_mlp2(const float* __restrict__ h, const float* __restrict__ W2,
             const float* __restrict__ b2,
             const int* __restrict__ sorted, const int* __restrict__ ch_agent,
             const int* __restrict__ ch_start, const int* __restrict__ ch_len,
             float* __restrict__ o_out)
{
    const int chunk = blockIdx.x;
    const int len = ch_len[chunk];
    if (len == 0) return;
    const int a  = ch_agent[chunk];
    const int cs = ch_start[chunk];
    const int t  = threadIdx.x;
    const int bcol = blockIdx.y * 64;

    __shared__ float hT[2][64 * XPAD];       // 10 KB, double-buffered h tile
    __shared__ float wS[2][64 * 64];         // 32 KB, double-buffered W tile
    __shared__ int   sid[SB];

    if (t < SB) sid[t] = sorted[cs + (t < len ? t : len - 1)];
    __syncthreads();

    const float* Wb = W2 + (size_t)a * HID_DIM * OUT_DIM + bcol;
    {   // stage pass 0 (both tiles) into buf 0
        const int row = t & 63;
        const int sb  = (t >> 6) * 4;
        #pragma unroll
        for (int j = 0; j < 4; ++j)
            hT[0][row * XPAD + sb + j] = h[(size_t)sid[sb + j] * HID_DIM + row];
        #pragma unroll
        for (int i = 0; i < 4; ++i) {
            const int id  = t + i * 256;
            const int r2  = id >> 4;
            const int c4  = (id & 15) * 4;
            *(float4*)(&wS[0][r2 * 64 + c4]) =
                *(const float4*)(Wb + (size_t)r2 * OUT_DIM + c4);
        }
    }
    __syncthreads();

    const int cg = t & 15;
    const int kq = (t >> 4) & 3;
    const int w  = t >> 6;
    const bool act = (w * 4) < len;

    float acc[16];
    #pragma unroll
    for (int i = 0; i < 16; ++i) acc[i] = 0.f;

    for (int p = 0; p < HID_DIM / 64; ++p) { // 8 passes
        if (p < 7) {                         // prefetch next tiles (other buf)
            const int nb = (p + 1) & 1;
            const int k0 = (p + 1) * 64;
            const int row = t & 63;
            const int sb  = (t >> 6) * 4;
            #pragma unroll
            for (int j = 0; j < 4; ++j)
                hT[nb][row * XPAD + sb + j] =
                    h[(size_t)sid[sb + j] * HID_DIM + k0 + row];
            const float* Wp = Wb + (size_t)k0 * OUT_DIM;
            #pragma unroll
            for (int i = 0; i < 4; ++i) {
                const int id  = t + i * 256;
                const int r2  = id >> 4;
                const int c4  = (id & 15) * 4;
                *(float4*)(&wS[nb][r2 * 64 + c4]) =
                    *(const float4*)(Wp + (size_t)r2 * OUT_DIM + c4);
            }
        }
        if (act) {
            const float* wb = wS[p & 1];
            const float* hb = hT[p & 1];
            #pragma unroll
            for (int i = 0; i < 16; ++i) {
                const int row = kq * 16 + i;
                const float4 wv = *(const float4*)(&wb[row * 64 + cg * 4]);
                const float4 xv = *(const float4*)(&hb[row * XPAD + w * 4]);
                const float wa[4] = {wv.x, wv.y, wv.z, wv.w};
                const float xa[4] = {xv.x, xv.y, xv.z, xv.w};
                #pragma unroll
                for (int c = 0; c < 4; ++c)
                    #pragma unroll
                    for (int s = 0; s < 4; ++s)
                        acc[c * 4 + s] = fmaf(wa[c], xa[s], acc[c * 4 + s]);
            }
        }
        __syncthreads();
    }

    if (!act) return;
    #pragma unroll
    for (int i = 0; i < 16; ++i) {
        acc[i] += __shfl_xor(acc[i], 16);
        acc[i] += __shfl_xor(acc[i], 32);
    }
    if (kq == 0) {
        const float4 bv = *(const float4*)(b2 + a * OUT_DIM + bcol + cg * 4);
        #pragma unroll
        for (int s = 0; s < 4; ++s) {
            float4 v = make_float4(acc[0 * 4 + s] + bv.x, acc[1 * 4 + s] + bv.y,
                                   acc[2 * 4 + s] + bv.z, acc[3 * 4 + s] + bv.w);
            *(float4*)(o_out + (size_t)sid[w * 4 + s] * OUT_DIM + bcol + cg * 4) = v;
        }
    }
}

extern "C" void kernel_launch(void* const* d_in, const int* in_sizes, int n_in,
                              void* d_out, int out_size, void* d_ws, size_t ws_size,
                              hipStream_t stream) {
    const float* x  = (const float*)d_in[0];
    const float* W1 = (const float*)d_in[1];
    const float* b1 = (const float*)d_in[2];
    const float* W2 = (const float*)d_in[3];
    const float* b2 = (const float*)d_in[4];
    const float* rw = (const float*)d_in[5];
    const int* raw  = (const int*)d_in[6];

    int* ws       = (int*)d_ws;
    int* sorted   = ws;            // [1024]
    int* ch_agent = ws + 1024;     // [128]
    int* ch_start = ws + 1152;     // [128]
    int* ch_len   = ws + 1280;     // [128]

    float* out   = (float*)d_out;
    float* h_out = out;                                   // [B, HID]
    float* o_out = h_out + (size_t)BATCH * HID_DIM;       // [B, OUT]
    float* r_out = o_out + (size_t)BATCH * OUT_DIM;       // [B, C]

    // router accumulates via atomics -> zero it (async memset is capture-safe)
    hipMemsetAsync(r_out, 0, (size_t)BATCH * N_CHILD * sizeof(float), stream);
    hipLaunchKernelGGL(prep_sort, dim3(1), dim3(1024), 0, stream,
                       raw, sorted, ch_agent, ch_start, ch_len);
    hipLaunchKernelGGL(k1_mlp1, dim3(MAXCH, 8), dim3(256), 0, stream,
                       x, W1, b1, rw, sorted, ch_agent, ch_start, ch_len,
                       h_out, r_out);
    hipLaunchKernelGGL(k2_mlp2, dim3(MAXCH, 4), dim3(256), 0, stream,
                       h_out, W2, b2, sorted, ch_agent, ch_start, ch_len, o_out);
}

// Round 9
// 134.128 us; speedup vs baseline: 1.3102x; 1.0741x over previous
//
#include <hip/hip_runtime.h>

#define IN_DIM   256
#define HID_DIM  512
#define OUT_DIM  256
#define N_CHILD  8
#define BATCH    1024

#define SB    16   // samples per chunk
#define XPAD  20   // [k][s] LDS stride: 16B-aligned float4 groups
#define MAXCH 128  // sum ceil(n_a/16) <= (1024 + 64*15)/16 = 124 < 128

// ---------------- prep: counting-sort samples by agent, build chunk list ----
// agent_indices may be int32 or int64 (jax_enable_x64): view as int32; if any
// odd word != 0 it's int32, else int64 (odd slots are zero high words).
// Chunk list built by a wave-wide prefix scan (no serial thread-0 loop).
extern "C" __global__ __launch_bounds__(1024)
void prep_sort(const int* __restrict__ raw, int* __restrict__ sorted,
               int* __restrict__ ch_agent, int* __restrict__ ch_start,
               int* __restrict__ ch_len)
{
    __shared__ int cnt[64], cnt2[64], start[64];
    __shared__ int is32, totch;
    const int t = threadIdx.x;
    if (t < 64) { cnt[t] = 0; cnt2[t] = 0; }
    if (t == 0) is32 = 0;
    __syncthreads();
    if (raw[2 * (t & 511) + 1] != 0) is32 = 1;   // benign shared race
    __syncthreads();
    const int a = (is32 ? raw[t] : raw[2 * t]) & 63;
    atomicAdd(&cnt[a], 1);
    __syncthreads();
    if (t < 64) {                                 // wave 0: dual prefix scan
        const int c   = cnt[t];
        const int nch = (c + SB - 1) / SB;
        int sc = c, sn = nch;
        #pragma unroll
        for (int d = 1; d < 64; d <<= 1) {
            const int vc = __shfl_up(sc, d);
            const int vn = __shfl_up(sn, d);
            if (t >= d) { sc += vc; sn += vn; }
        }
        const int off = sc - c;
        start[t] = off;
        const int chb = sn - nch;
        for (int p = 0, j = 0; p < c; p += SB, ++j) {
            ch_agent[chb + j] = t;
            ch_start[chb + j] = off + p;
            ch_len[chb + j]   = (c - p < SB) ? (c - p) : SB;
        }
        if (t == 63) totch = sn;
    }
    __syncthreads();
    if (t >= totch && t < MAXCH) ch_len[t] = 0;
    const int pos = start[a] + atomicAdd(&cnt2[a], 1);
    sorted[pos] = t;
}

// ---------------- K1: H = relu(X @ W1[a] + b1[a]); R += H @ rw[a] -----------
// grid (MAXCH, 8 tiles of 64 cols), 256 thr = 4 waves.
// lane map: cg=t&15 (4 cols), kq=(t>>4)&3 (in-wave K-split), wave=t>>6 owns
// samples 4w..4w+3 (gating). W double-buffered per 64-row pass; x staged once.
extern "C" __global__ __launch_bounds__(256)
void k1_mlp1(const float* __restrict__ x, const float* __restrict__ W1,
             const float* __restrict__ b1, const float* __restrict__ rw,
             const int* __restrict__ sorted, const int* __restrict__ ch_agent,
             const int* __restrict__ ch_start, const int* __restrict__ ch_len,
             float* __restrict__ h_out, float* __restrict__ r_out)
{
    const int chunk = blockIdx.x;
    const int len = ch_len[chunk];
    if (len == 0) return;
    const int a  = ch_agent[chunk];
    const int cs = ch_start[chunk];
    const int t  = threadIdx.x;
    const int bcol = blockIdx.y * 64;

    __shared__ float xT[IN_DIM * XPAD];      // 20 KB, [k][s], staged once
    __shared__ float wS[2][64 * 64];         // 32 KB, double-buffered W tile
    __shared__ int   sid[SB];

    if (t < SB) sid[t] = sorted[cs + (t < len ? t : len - 1)];   // pad = dup
    __syncthreads();

    #pragma unroll
    for (int s = 0; s < SB; ++s)
        xT[t * XPAD + s] = x[(size_t)sid[s] * IN_DIM + t];

    const float* Wb = W1 + (size_t)a * IN_DIM * HID_DIM + bcol;
    #pragma unroll
    for (int i = 0; i < 4; ++i) {
        const int id  = t + i * 256;
        const int row = id >> 4;
        const int c4  = (id & 15) * 4;
        *(float4*)(&wS[0][row * 64 + c4]) =
            *(const float4*)(Wb + (size_t)row * HID_DIM + c4);
    }
    __syncthreads();

    const int cg = t & 15;
    const int kq = (t >> 4) & 3;
    const int w  = t >> 6;
    const bool act = (w * 4) < len;

    float acc[16];
    #pragma unroll
    for (int i = 0; i < 16; ++i) acc[i] = 0.f;

    for (int p = 0; p < IN_DIM / 64; ++p) {
        if (p < 3) {
            const int nb = (p + 1) & 1;
            const float* Wp = Wb + (size_t)(p + 1) * 64 * HID_DIM;
            #pragma unroll
            for (int i = 0; i < 4; ++i) {
                const int id  = t + i * 256;
                const int row = id >> 4;
                const int c4  = (id & 15) * 4;
                *(float4*)(&wS[nb][row * 64 + c4]) =
                    *(const float4*)(Wp + (size_t)row * HID_DIM + c4);
            }
        }
        if (act) {
            const float* wb = wS[p & 1];
            #pragma unroll
            for (int i = 0; i < 16; ++i) {
                const int row = kq * 16 + i;
                const float4 wv = *(const float4*)(&wb[row * 64 + cg * 4]);
                const float4 xv = *(const float4*)(&xT[(p * 64 + row) * XPAD + w * 4]);
                const float wa[4] = {wv.x, wv.y, wv.z, wv.w};
                const float xa[4] = {xv.x, xv.y, xv.z, xv.w};
                #pragma unroll
                for (int c = 0; c < 4; ++c)
                    #pragma unroll
                    for (int s = 0; s < 4; ++s)
                        acc[c * 4 + s] = fmaf(wa[c], xa[s], acc[c * 4 + s]);
            }
        }
        __syncthreads();
    }

    if (!act) return;

    #pragma unroll
    for (int i = 0; i < 16; ++i) {
        acc[i] += __shfl_xor(acc[i], 16);
        acc[i] += __shfl_xor(acc[i], 32);
    }

    const float4 bv = *(const float4*)(b1 + a * HID_DIM + bcol + cg * 4);
    const float ba[4] = {bv.x, bv.y, bv.z, bv.w};
    float hv[16];
    #pragma unroll
    for (int c = 0; c < 4; ++c)
        #pragma unroll
        for (int s = 0; s < 4; ++s)
            hv[c * 4 + s] = fmaxf(acc[c * 4 + s] + ba[c], 0.f);

    if (kq == 0) {
        #pragma unroll
        for (int s = 0; s < 4; ++s) {
            float4 v = make_float4(hv[0 * 4 + s], hv[1 * 4 + s],
                                   hv[2 * 4 + s], hv[3 * 4 + s]);
            *(float4*)(h_out + (size_t)sid[w * 4 + s] * HID_DIM + bcol + cg * 4) = v;
        }
    }

    float rp[32];                            // router partials [s][ch]
    #pragma unroll
    for (int i = 0; i < 32; ++i) rp[i] = 0.f;
    const float* rwa = rw + (size_t)a * HID_DIM * N_CHILD + (size_t)(bcol + cg * 4) * N_CHILD;
    #pragma unroll
    for (int j = 0; j < 4; ++j)
        #pragma unroll
        for (int ch = 0; ch < 8; ++ch) {
            const float rv = rwa[j * N_CHILD + ch];
            #pragma unroll
            for (int s = 0; s < 4; ++s)
                rp[s * 8 + ch] = fmaf(hv[j * 4 + s], rv, rp[s * 8 + ch]);
        }
    #pragma unroll
    for (int i = 0; i < 32; ++i) {
        rp[i] += __shfl_xor(rp[i], 1);
        rp[i] += __shfl_xor(rp[i], 2);
        rp[i] += __shfl_xor(rp[i], 4);
        rp[i] += __shfl_xor(rp[i], 8);
    }
    if (cg == 0 && kq == 0) {
        #pragma unroll
        for (int s = 0; s < 4; ++s) {
            const int sg = w * 4 + s;
            if (sg < len) {
                float* rdst = r_out + (size_t)sid[sg] * N_CHILD;
                #pragma unroll
                for (int ch = 0; ch < 8; ++ch)
                    atomicAdd(rdst + ch, rp[s * 8 + ch]);
            }
        }
    }
}

// ---------------- K2: OUT += H @ W2[a] (+ b2[a] on half 0)  (512 -> 256) ----
// grid (MAXCH, 4 tiles of 64 cols, 2 K-halves), 256 thr. Each block does
// 4 dbuf passes over its 256-row K-half; partials atomicAdd'ed into o_out
// (zeroed by memset). Strict per-sample gating (dup slots must not add).
extern "C" __global__ __launch_bounds__(256)
void k2_mlp2(const float* __restrict__ h, const float* __restrict__ W2,
             const float* __restrict__ b2,
             const int* __restrict__ sorted, const int* __restrict__ ch_agent,
             const int* __restrict__ ch_start, const int* __restrict__ ch_len,
             float* __restrict__ o_out)
{
    const int chunk = blockIdx.x;
    const int len = ch_len[chunk];
    if (len == 0) return;
    const int a  = ch_agent[chunk];
    const int cs = ch_start[chunk];
    const int t  = threadIdx.x;
    const int bcol = blockIdx.y * 64;
    const int kb   = blockIdx.z * 256;       // K-half base

    __shared__ float hT[2][64 * XPAD];       // 10 KB, double-buffered h tile
    __shared__ float wS[2][64 * 64];         // 32 KB, double-buffered W tile
    __shared__ int   sid[SB];

    if (t < SB) sid[t] = sorted[cs + (t < len ? t : len - 1)];
    __syncthreads();

    const float* Wb = W2 + (size_t)a * HID_DIM * OUT_DIM + bcol;
    {   // stage pass 0 into buf 0
        const int row = t & 63;
        const int sb  = (t >> 6) * 4;
        #pragma unroll
        for (int j = 0; j < 4; ++j)
            hT[0][row * XPAD + sb + j] =
                h[(size_t)sid[sb + j] * HID_DIM + kb + row];
        #pragma unroll
        for (int i = 0; i < 4; ++i) {
            const int id  = t + i * 256;
            const int r2  = id >> 4;
            const int c4  = (id & 15) * 4;
            *(float4*)(&wS[0][r2 * 64 + c4]) =
                *(const float4*)(Wb + (size_t)(kb + r2) * OUT_DIM + c4);
        }
    }
    __syncthreads();

    const int cg = t & 15;
    const int kq = (t >> 4) & 3;
    const int w  = t >> 6;
    const bool act = (w * 4) < len;

    float acc[16];
    #pragma unroll
    for (int i = 0; i < 16; ++i) acc[i] = 0.f;

    for (int p = 0; p < 4; ++p) {            // 4 passes over this K-half
        if (p < 3) {
            const int nb = (p + 1) & 1;
            const int k0 = kb + (p + 1) * 64;
            const int row = t & 63;
            const int sb  = (t >> 6) * 4;
            #pragma unroll
            for (int j = 0; j < 4; ++j)
                hT[nb][row * XPAD + sb + j] =
                    h[(size_t)sid[sb + j] * HID_DIM + k0 + row];
            const float* Wp = Wb + (size_t)k0 * OUT_DIM;
            #pragma unroll
            for (int i = 0; i < 4; ++i) {
                const int id  = t + i * 256;
                const int r2  = id >> 4;
                const int c4  = (id & 15) * 4;
                *(float4*)(&wS[nb][r2 * 64 + c4]) =
                    *(const float4*)(Wp + (size_t)r2 * OUT_DIM + c4);
            }
        }
        if (act) {
            const float* wb = wS[p & 1];
            const float* hb = hT[p & 1];
            #pragma unroll
            for (int i = 0; i < 16; ++i) {
                const int row = kq * 16 + i;
                const float4 wv = *(const float4*)(&wb[row * 64 + cg * 4]);
                const float4 xv = *(const float4*)(&hb[row * XPAD + w * 4]);
                const float wa[4] = {wv.x, wv.y, wv.z, wv.w};
                const float xa[4] = {xv.x, xv.y, xv.z, xv.w};
                #pragma unroll
                for (int c = 0; c < 4; ++c)
                    #pragma unroll
                    for (int s = 0; s < 4; ++s)
                        acc[c * 4 + s] = fmaf(wa[c], xa[s], acc[c * 4 + s]);
            }
        }
        __syncthreads();
    }

    if (!act) return;
    #pragma unroll
    for (int i = 0; i < 16; ++i) {
        acc[i] += __shfl_xor(acc[i], 16);
        acc[i] += __shfl_xor(acc[i], 32);
    }
    if (kq == 0) {
        float4 bv = make_float4(0.f, 0.f, 0.f, 0.f);
        if (blockIdx.z == 0)                 // bias added exactly once
            bv = *(const float4*)(b2 + a * OUT_DIM + bcol + cg * 4);
        #pragma unroll
        for (int s = 0; s < 4; ++s) {
            const int g = w * 4 + s;
            if (g < len) {                   // strict gating: dups must not add
                float* op = o_out + (size_t)sid[g] * OUT_DIM + bcol + cg * 4;
                atomicAdd(op + 0, acc[0 * 4 + s] + bv.x);
                atomicAdd(op + 1, acc[1 * 4 + s] + bv.y);
                atomicAdd(op + 2, acc[2 * 4 + s] + bv.z);
                atomicAdd(op + 3, acc[3 * 4 + s] + bv.w);
            }
        }
    }
}

extern "C" void kernel_launch(void* const* d_in, const int* in_sizes, int n_in,
                              void* d_out, int out_size, void* d_ws, size_t ws_size,
                              hipStream_t stream) {
    const float* x  = (const float*)d_in[0];
    const float* W1 = (const float*)d_in[1];
    const float* b1 = (const float*)d_in[2];
    const float* W2 = (const float*)d_in[3];
    const float* b2 = (const float*)d_in[4];
    const float* rw = (const float*)d_in[5];
    const int* raw  = (const int*)d_in[6];

    int* ws       = (int*)d_ws;
    int* sorted   = ws;            // [1024]
    int* ch_agent = ws + 1024;     // [128]
    int* ch_start = ws + 1152;     // [128]
    int* ch_len   = ws + 1280;     // [128]

    float* out   = (float*)d_out;
    float* h_out = out;                                   // [B, HID]
    float* o_out = h_out + (size_t)BATCH * HID_DIM;       // [B, OUT]
    float* r_out = o_out + (size_t)BATCH * OUT_DIM;       // [B, C]

    // o_out and r_out are contiguous and both accumulate via atomics: one memset
    hipMemsetAsync(o_out, 0,
                   (size_t)BATCH * (OUT_DIM + N_CHILD) * sizeof(float), stream);
    hipLaunchKernelGGL(prep_sort, dim3(1), dim3(1024), 0, stream,
                       raw, sorted, ch_agent, ch_start, ch_len);
    hipLaunchKernelGGL(k1_mlp1, dim3(MAXCH, 8), dim3(256), 0, stream,
                       x, W1, b1, rw, sorted, ch_agent, ch_start, ch_len,
                       h_out, r_out);
    hipLaunchKernelGGL(k2_mlp2, dim3(MAXCH, 4, 2), dim3(256), 0, stream,
                       h_out, W2, b2, sorted, ch_agent, ch_start, ch_len, o_out);
}

// Round 10
// 132.624 us; speedup vs baseline: 1.3251x; 1.0113x over previous
//
#include <hip/hip_runtime.h>

#define IN_DIM   256
#define HID_DIM  512
#define OUT_DIM  256
#define N_CHILD  8
#define BATCH    1024

#define SB    16   // samples per chunk
#define XPAD  20   // [k][s] LDS stride: 16B-aligned float4 groups
#define MAXCH 128  // sum ceil(n_a/16) <= (1024 + 64*15)/16 = 124 < 128

// ---------------- prep: sort samples by agent + zero atomic outputs ---------
// grid (5): block 0 = counting sort + chunk list (wave-wide prefix scan);
// blocks 1-4 = zero o_out/r_out (k2 router/out accumulate via atomics).
// agent_indices may be int32 or int64 (jax_enable_x64): view as int32; if any
// odd word != 0 it's int32, else int64 (odd slots are zero high words).
extern "C" __global__ __launch_bounds__(1024)
void prep_sort(const int* __restrict__ raw, int* __restrict__ sorted,
               int* __restrict__ ch_agent, int* __restrict__ ch_start,
               int* __restrict__ ch_len, float* __restrict__ zdst)
{
    const int t = threadIdx.x;
    if (blockIdx.x > 0) {                         // zero 1.06 MB in 3 blocks... 4
        const int total4 = (BATCH * (OUT_DIM + N_CHILD)) / 4;   // 67584 float4
        const float4 z = make_float4(0.f, 0.f, 0.f, 0.f);
        for (int i = (blockIdx.x - 1) * 1024 + t; i < total4; i += 4 * 1024)
            ((float4*)zdst)[i] = z;
        return;
    }
    __shared__ int cnt[64], cnt2[64], start[64];
    __shared__ int is32, totch;
    if (t < 64) { cnt[t] = 0; cnt2[t] = 0; }
    if (t == 0) is32 = 0;
    __syncthreads();
    if (raw[2 * (t & 511) + 1] != 0) is32 = 1;   // benign shared race
    __syncthreads();
    const int a = (is32 ? raw[t] : raw[2 * t]) & 63;
    atomicAdd(&cnt[a], 1);
    __syncthreads();
    if (t < 64) {                                 // wave 0: dual prefix scan
        const int c   = cnt[t];
        const int nch = (c + SB - 1) / SB;
        int sc = c, sn = nch;
        #pragma unroll
        for (int d = 1; d < 64; d <<= 1) {
            const int vc = __shfl_up(sc, d);
            const int vn = __shfl_up(sn, d);
            if (t >= d) { sc += vc; sn += vn; }
        }
        const int off = sc - c;
        start[t] = off;
        const int chb = sn - nch;
        for (int p = 0, j = 0; p < c; p += SB, ++j) {
            ch_agent[chb + j] = t;
            ch_start[chb + j] = off + p;
            ch_len[chb + j]   = (c - p < SB) ? (c - p) : SB;
        }
        if (t == 63) totch = sn;
    }
    __syncthreads();
    if (t >= totch && t < MAXCH) ch_len[t] = 0;
    const int pos = start[a] + atomicAdd(&cnt2[a], 1);
    sorted[pos] = t;
}

// ---------------- K1: H = relu(X @ W1[a] + b1[a]); R += H @ rw[a] -----------
// grid (MAXCH, 8 tiles of 64 cols), 256 thr = 4 waves. LDS 36.9 KB -> 4 blk/CU
// (992 blocks all co-resident, single round). Single-buffered W staging;
// inter-block waves hide the barrier drains.
// lane map: cg=t&15 (4 cols), kq=(t>>4)&3 (K-split, kq-CONTIGUOUS rows i*4+kq
// for LDS bank spread), wave w=t>>6 owns samples 4w..4w+3 (gating).
extern "C" __global__ __launch_bounds__(256)
void k1_mlp1(const float* __restrict__ x, const float* __restrict__ W1,
             const float* __restrict__ b1, const float* __restrict__ rw,
             const int* __restrict__ sorted, const int* __restrict__ ch_agent,
             const int* __restrict__ ch_start, const int* __restrict__ ch_len,
             float* __restrict__ h_out, float* __restrict__ r_out)
{
    const int chunk = blockIdx.x;
    const int len = ch_len[chunk];
    if (len == 0) return;
    const int a  = ch_agent[chunk];
    const int cs = ch_start[chunk];
    const int t  = threadIdx.x;
    const int bcol = blockIdx.y * 64;

    __shared__ float xT[IN_DIM * XPAD];      // 20 KB, [k][s], staged once
    __shared__ float wS[64 * 64];            // 16 KB, single-buffered W tile
    __shared__ int   sid[SB];

    if (t < SB) sid[t] = sorted[cs + (t < len ? t : len - 1)];   // pad = dup
    __syncthreads();

    #pragma unroll
    for (int s = 0; s < SB; ++s)
        xT[t * XPAD + s] = x[(size_t)sid[s] * IN_DIM + t];       // coalesced

    const float* Wb = W1 + (size_t)a * IN_DIM * HID_DIM + bcol;
    const int cg = t & 15;
    const int kq = (t >> 4) & 3;
    const int w  = t >> 6;
    const bool act = (w * 4) < len;

    float acc[16];
    #pragma unroll
    for (int i = 0; i < 16; ++i) acc[i] = 0.f;

    for (int p = 0; p < IN_DIM / 64; ++p) {  // 4 passes of 64 k-rows
        __syncthreads();                     // wS reusable (covers xT at p==0)
        #pragma unroll
        for (int i = 0; i < 4; ++i) {        // stage 16 KB W tile
            const int id  = t + i * 256;
            const int row = id >> 4;
            const int c4  = (id & 15) * 4;
            *(float4*)(&wS[row * 64 + c4]) =
                *(const float4*)(Wb + (size_t)(p * 64 + row) * HID_DIM + c4);
        }
        __syncthreads();
        if (act) {
            #pragma unroll
            for (int i = 0; i < 16; ++i) {
                const int row = i * 4 + kq;  // kq-contiguous: bank spread
                const float4 wv = *(const float4*)(&wS[row * 64 + cg * 4]);
                const float4 xv = *(const float4*)(&xT[(p * 64 + row) * XPAD + w * 4]);
                const float wa[4] = {wv.x, wv.y, wv.z, wv.w};
                const float xa[4] = {xv.x, xv.y, xv.z, xv.w};
                #pragma unroll
                for (int c = 0; c < 4; ++c)
                    #pragma unroll
                    for (int s = 0; s < 4; ++s)
                        acc[c * 4 + s] = fmaf(wa[c], xa[s], acc[c * 4 + s]);
            }
        }
    }

    if (!act) return;

    #pragma unroll
    for (int i = 0; i < 16; ++i) {           // reduce over kq (lane bits 4-5)
        acc[i] += __shfl_xor(acc[i], 16);
        acc[i] += __shfl_xor(acc[i], 32);
    }

    if (kq != 0) return;                     // epilogue on kq==0 lanes only

    const float4 bv = *(const float4*)(b1 + a * HID_DIM + bcol + cg * 4);
    const float ba[4] = {bv.x, bv.y, bv.z, bv.w};
    float hv[16];
    #pragma unroll
    for (int c = 0; c < 4; ++c)
        #pragma unroll
        for (int s = 0; s < 4; ++s)
            hv[c * 4 + s] = fmaxf(acc[c * 4 + s] + ba[c], 0.f);

    #pragma unroll
    for (int s = 0; s < 4; ++s) {            // dup-slot writes identical
        float4 v = make_float4(hv[0 * 4 + s], hv[1 * 4 + s],
                               hv[2 * 4 + s], hv[3 * 4 + s]);
        *(float4*)(h_out + (size_t)sid[w * 4 + s] * HID_DIM + bcol + cg * 4) = v;
    }

    float rp[32];                            // router partials [s][ch]
    #pragma unroll
    for (int i = 0; i < 32; ++i) rp[i] = 0.f;
    const float* rwa = rw + (size_t)a * HID_DIM * N_CHILD
                          + (size_t)(bcol + cg * 4) * N_CHILD;
    #pragma unroll
    for (int j = 0; j < 4; ++j)
        #pragma unroll
        for (int ch = 0; ch < 8; ++ch) {
            const float rv = rwa[j * N_CHILD + ch];
            #pragma unroll
            for (int s = 0; s < 4; ++s)
                rp[s * 8 + ch] = fmaf(hv[j * 4 + s], rv, rp[s * 8 + ch]);
        }
    #pragma unroll
    for (int i = 0; i < 32; ++i) {           // reduce over cg (lane bits 0-3)
        rp[i] += __shfl_xor(rp[i], 1);
        rp[i] += __shfl_xor(rp[i], 2);
        rp[i] += __shfl_xor(rp[i], 4);
        rp[i] += __shfl_xor(rp[i], 8);
    }
    if (cg == 0) {
        #pragma unroll
        for (int s = 0; s < 4; ++s) {
            const int sg = w * 4 + s;
            if (sg < len) {                  // strict gating for atomics
                float* rdst = r_out + (size_t)sid[sg] * N_CHILD;
                #pragma unroll
                for (int ch = 0; ch < 8; ++ch)
                    atomicAdd(rdst + ch, rp[s * 8 + ch]);
            }
        }
    }
}

// ---------------- K2: OUT += H @ W2[a] (+ b2[a] on half 0)  (512 -> 256) ----
// grid (MAXCH, 4 tiles of 64 cols, 2 K-halves), 256 thr. LDS 21.6 KB ->
// 7 blk/CU, all 992 blocks co-resident. Single-buffered staging; partials
// atomicAdd'ed into zeroed o_out; strict per-sample gating.
extern "C" __global__ __launch_bounds__(256)
void k2_mlp2(const float* __restrict__ h, const float* __restrict__ W2,
             const float* __restrict__ b2,
             const int* __restrict__ sorted, const int* __restrict__ ch_agent,
             const int* __restrict__ ch_start, const int* __restrict__ ch_len,
             float* __restrict__ o_out)
{
    const int chunk = blockIdx.x;
    const int len = ch_len[chunk];
    if (len == 0) return;
    const int a  = ch_agent[chunk];
    const int cs = ch_start[chunk];
    const int t  = threadIdx.x;
    const int bcol = blockIdx.y * 64;
    const int kb   = blockIdx.z * 256;       // K-half base

    __shared__ float hT[64 * XPAD];          // 5 KB, per-pass h tile
    __shared__ float wS[64 * 64];            // 16 KB, per-pass W tile
    __shared__ int   sid[SB];

    if (t < SB) sid[t] = sorted[cs + (t < len ? t : len - 1)];
    __syncthreads();

    const float* Wb = W2 + (size_t)a * HID_DIM * OUT_DIM + bcol;
    const int cg = t & 15;
    const int kq = (t >> 4) & 3;
    const int w  = t >> 6;
    const bool act = (w * 4) < len;

    float acc[16];
    #pragma unroll
    for (int i = 0; i < 16; ++i) acc[i] = 0.f;

    for (int p = 0; p < 4; ++p) {            // 4 passes over this K-half
        const int k0 = kb + p * 64;
        __syncthreads();                     // tiles reusable
        {
            const int row = t & 63;
            const int sb  = (t >> 6) * 4;
            #pragma unroll
            for (int j = 0; j < 4; ++j)      // stage h rows (coalesced over k)
                hT[row * XPAD + sb + j] =
                    h[(size_t)sid[sb + j] * HID_DIM + k0 + row];
        }
        #pragma unroll
        for (int i = 0; i < 4; ++i) {        // stage 16 KB W tile
            const int id  = t + i * 256;
            const int r2  = id >> 4;
            const int c4  = (id & 15) * 4;
            *(float4*)(&wS[r2 * 64 + c4]) =
                *(const float4*)(Wb + (size_t)(k0 + r2) * OUT_DIM + c4);
        }
        __syncthreads();
        if (act) {
            #pragma unroll
            for (int i = 0; i < 16; ++i) {
                const int row = i * 4 + kq;  // kq-contiguous: bank spread
                const float4 wv = *(const float4*)(&wS[row * 64 + cg * 4]);
                const float4 xv = *(const float4*)(&hT[row * XPAD + w * 4]);
                const float wa[4] = {wv.x, wv.y, wv.z, wv.w};
                const float xa[4] = {xv.x, xv.y, xv.z, xv.w};
                #pragma unroll
                for (int c = 0; c < 4; ++c)
                    #pragma unroll
                    for (int s = 0; s < 4; ++s)
                        acc[c * 4 + s] = fmaf(wa[c], xa[s], acc[c * 4 + s]);
            }
        }
    }

    if (!act) return;
    #pragma unroll
    for (int i = 0; i < 16; ++i) {
        acc[i] += __shfl_xor(acc[i], 16);
        acc[i] += __shfl_xor(acc[i], 32);
    }
    if (kq == 0) {
        float4 bv = make_float4(0.f, 0.f, 0.f, 0.f);
        if (blockIdx.z == 0)                 // bias added exactly once
            bv = *(const float4*)(b2 + a * OUT_DIM + bcol + cg * 4);
        #pragma unroll
        for (int s = 0; s < 4; ++s) {
            const int g = w * 4 + s;
            if (g < len) {                   // strict gating: dups must not add
                float* op = o_out + (size_t)sid[g] * OUT_DIM + bcol + cg * 4;
                atomicAdd(op + 0, acc[0 * 4 + s] + bv.x);
                atomicAdd(op + 1, acc[1 * 4 + s] + bv.y);
                atomicAdd(op + 2, acc[2 * 4 + s] + bv.z);
                atomicAdd(op + 3, acc[3 * 4 + s] + bv.w);
            }
        }
    }
}

extern "C" void kernel_launch(void* const* d_in, const int* in_sizes, int n_in,
                              void* d_out, int out_size, void* d_ws, size_t ws_size,
                              hipStream_t stream) {
    const float* x  = (const float*)d_in[0];
    const float* W1 = (const float*)d_in[1];
    const float* b1 = (const float*)d_in[2];
    const float* W2 = (const float*)d_in[3];
    const float* b2 = (const float*)d_in[4];
    const float* rw = (const float*)d_in[5];
    const int* raw  = (const int*)d_in[6];

    int* ws       = (int*)d_ws;
    int* sorted   = ws;            // [1024]
    int* ch_agent = ws + 1024;     // [128]
    int* ch_start = ws + 1152;     // [128]
    int* ch_len   = ws + 1280;     // [128]

    float* out   = (float*)d_out;
    float* h_out = out;                                   // [B, HID]
    float* o_out = h_out + (size_t)BATCH * HID_DIM;       // [B, OUT]
    float* r_out = o_out + (size_t)BATCH * OUT_DIM;       // [B, C]

    hipLaunchKernelGGL(prep_sort, dim3(5), dim3(1024), 0, stream,
                       raw, sorted, ch_agent, ch_start, ch_len, o_out);
    hipLaunchKernelGGL(k1_mlp1, dim3(MAXCH, 8), dim3(256), 0, stream,
                       x, W1, b1, rw, sorted, ch_agent, ch_start, ch_len,
                       h_out, r_out);
    hipLaunchKernelGGL(k2_mlp2, dim3(MAXCH, 4, 2), dim3(256), 0, stream,
                       h_out, W2, b2, sorted, ch_agent, ch_start, ch_len, o_out);
}